// Round 8
// baseline (134.240 us; speedup 1.0000x reference)
//
#include <hip/hip_runtime.h>

#define CCH   256
#define FH    96
#define FW    96
#define HW    (FH*FW)
#define SCALE 0.0625f

#define HROWS 21              // max window rows
#define PSLOT 128             // 16B slots per plane (2 KiB); nslotS <= 128 guaranteed
#define NPLN  3               // plane ring -> prefetch depth 2
#define WVF   (NPLN*PSLOT*4)  // floats per wave (1536)
#define WCH   32              // channels per wave (block = 128ch half-roi, 4 waves)

// R8: async global->LDS staging (global_load_lds) with a 3-plane ring and
// hand-counted vmcnt waits. Register deep-prefetch is compiler-dead (R1
// sunk / R3 spilled); the DMA path has no register results to sink or
// spill. Loads for channel c+2 issue at the top of iter c -> ~2 iterations
// (~400-500cy) of lead, covering HBM-class latency that the old 1-deep
// pipeline (~150cy lead) exposed. LDS layout: linear lane->slot inside a
// plane, but slot=(r,q) with ODD row stride sQ (pad slots q in [cwq,sQ)
// absorb clamped duplicate loads) -> R4's bank profile preserved. Every
// readable slot is written with finite data (pads = clamped real data;
// nslotS never equals 64/128 since sQ odd/6) -> zero-init dropped.
// vmcnt counting (in-order retirement): per-iter ops after loads(c) =
// store(c-2), loads(c+1), store(c-1), loads(c+2) = 2L+2 steady; peeled
// prologue waits 2L, 2L+1; epilogue L+2, 2. L in {1,2} block-uniform.
// Kept frozen: R4 adaptive width, identity mapping, 49-lane compute
// (8 ds_read2 + 16 FMA). Dropped: bucket sort (R5: FETCH -73MB, dur flat),
// quarter-split (R7: +1us only; half-roi halves prologue overhead here).
#define GLOBAL_AS __attribute__((address_space(1)))
#define LDS_AS    __attribute__((address_space(3)))

__device__ __forceinline__ void async16(const float* g, float* l) {
    // lane i's 16B -> ldsbase + i*16 (wave-uniform LDS base, per-lane global src)
    __builtin_amdgcn_global_load_lds((const GLOBAL_AS void*)g, (LDS_AS void*)l, 16, 0, 0);
}

#define VMW(n) asm volatile("s_waitcnt vmcnt(" #n ")" ::: "memory")

__global__ __launch_bounds__(256, 6)
void roialign_kernel(const float* __restrict__ feat,
                     const float* __restrict__ rois,
                     float* __restrict__ out)
{
    __shared__ __align__(16) float win[4 * WVF];   // 24 KiB
    __shared__ int   s_lo[2][14];
    __shared__ float s_wl[2][14], s_wh[2][14];

    const int k    = blockIdx.x >> 1;    // identity mapping
    const int half = blockIdx.x & 1;
    const int tid  = threadIdx.x;
    const int w    = tid >> 6;
    const int ll   = tid & 63;

    // ---------- Phase A: per-roi sample coords ----------
    const float x1 = rois[k*5+1] * SCALE;
    const float y1 = rois[k*5+2] * SCALE;
    const float x2 = rois[k*5+3] * SCALE;
    const float y2 = rois[k*5+4] * SCALE;
    const int   b  = (int)rois[k*5+0];
    const float binw = fmaxf(x2 - x1, 1.0f) * (1.0f/7.0f);
    const float binh = fmaxf(y2 - y1, 1.0f) * (1.0f/7.0f);

    if (tid < 28) {
        const int   axis  = (tid >= 14) ? 1 : 0;
        const int   g     = axis ? tid - 14 : tid;
        const float start = axis ? x1 : y1;
        const float bsz   = axis ? binw : binh;
        const float offs  = (float)(g >> 1) + 0.25f + 0.5f*(float)(g & 1);
        const float coord = start + bsz * offs;
        const bool  valid = (coord >= -1.0f) && (coord <= 96.0f);
        const float cc    = fminf(fmaxf(coord, 0.0f), 95.0f);
        const float lof   = floorf(cc);
        const float frac  = cc - lof;
        const float v     = valid ? 1.0f : 0.0f;
        s_lo[axis][g] = (int)lof;
        s_wl[axis][g] = (1.0f - frac) * v;
        s_wh[axis][g] = frac * v;
    }
    __syncthreads();   // the ONLY barrier

    // ---------- adaptive window geometry (block-uniform) ----------
    const int row0   = s_lo[0][0];
    const int col0   = s_lo[1][0] & ~3;               // 16B-aligned left edge
    const int colEnd = min(s_lo[1][13] + 1, FW-1);    // rightmost tap column
    const int width  = colEnd - col0 + 1;             // 1..24
    const int cwq    = min((width + 3) >> 2, 6);      // data quads per row, 1..6
    int sQ           = ((cwq + 1) & ~1) | 1;          // row stride quads: 3,3,5,5,7,7
    int hw_          = min(s_lo[0][13] + 1, FH-1) - row0 + 1;
    const int hwin   = min(hw_, HROWS);
    if (hwin * sQ > PSLOT) sQ = cwq;                  // rare giant-roi fallback (<=126)
    const int RS     = sQ * 4;                        // row stride in floats
    const int nslotS = hwin * sQ;                     // staged slots incl pads, <=128
    const bool LI2   = (nslotS > 64);                 // 2 staging instrs per channel?

    float* const wp = &win[w * WVF];

    // ---------- Phase B: tap addresses & pre-scaled weights (channel-invariant) ----------
    const bool active = ll < 49;
    const int  p  = active ? ll : 0;
    const int  oy = p / 7;
    const int  ox = p - oy*7;

    int   aL[4], aH[4];
    float w00[4], w01[4], w10[4], w11[4];
    #pragma unroll
    for (int sy = 0; sy < 2; ++sy) {
        const int   gy  = 2*oy + sy;
        const int   rlo = min(s_lo[0][gy] - row0,              hwin-1);
        const int   rhi = min(min(s_lo[0][gy]+1, FH-1) - row0, hwin-1);
        const float wyl = s_wl[0][gy], wyh = s_wh[0][gy];
        #pragma unroll
        for (int sx = 0; sx < 2; ++sx) {
            const int   gx  = 2*ox + sx;
            const int   clo = min(s_lo[1][gx] - col0, RS-2);   // <=width-2 provable
            const float wxl = s_wl[1][gx], wxh = s_wh[1][gx];
            const int   s   = sy*2 + sx;
            aL[s] = rlo*RS + clo;
            aH[s] = rhi*RS + clo;
            w00[s] = wyl*wxl*0.25f;  w01[s] = wyl*wxh*0.25f;   // 0.25 = sample mean
            w10[s] = wyh*wxl*0.25f;  w11[s] = wyh*wxh*0.25f;
        }
    }

    // ---------- staging source offsets: slot s = (r,q), linear lane->slot ----------
    // Pad/overflow slots load clamped duplicates (finite, never read as data).
    int soff0, soff1;
    {
        const int s0 = ll,      r0 = s0 / sQ, q0 = s0 - r0*sQ;
        const int s1 = ll + 64, r1 = s1 / sQ, q1 = s1 - r1*sQ;
        const int rc0 = min(r0, hwin-1), qc0 = min(q0, cwq-1);
        const int rc1 = min(r1, hwin-1), qc1 = min(q1, cwq-1);
        soff0 = min(row0 + rc0, FH-1)*FW + col0 + qc0*4;   // 16B-aligned, in-image
        soff1 = min(row0 + rc1, FH-1)*FW + col0 + qc1*4;
    }

    const int    cb   = half*128 + w*WCH;
    const float* gch  = feat + (size_t)(b*CCH + cb) * HW;
    float*       outp = out  + ((size_t)k*CCH + cb)*49 + p;

#define STAGE(cc, pl) do {                                              \
        const float* gs_ = gch + (size_t)(cc) * HW;                     \
        float* lp_ = wp + (pl) * (PSLOT*4);                             \
        async16(gs_ + soff0, lp_);                                      \
        if (LI2) async16(gs_ + soff1, lp_ + 256);                       \
    } while (0)

#define COMP(pl) do {                                                   \
        const float* bp_ = wp + (pl) * (PSLOT*4);                       \
        if (active) {                                                   \
            float t0 = w00[0]*bp_[aL[0]] + w01[0]*bp_[aL[0]+1]          \
                     + w10[0]*bp_[aH[0]] + w11[0]*bp_[aH[0]+1];         \
            float t1 = w00[1]*bp_[aL[1]] + w01[1]*bp_[aL[1]+1]          \
                     + w10[1]*bp_[aH[1]] + w11[1]*bp_[aH[1]+1];         \
            float t2 = w00[2]*bp_[aL[2]] + w01[2]*bp_[aL[2]+1]          \
                     + w10[2]*bp_[aH[2]] + w11[2]*bp_[aH[2]+1];         \
            float t3 = w00[3]*bp_[aL[3]] + w01[3]*bp_[aL[3]+1]          \
                     + w10[3]*bp_[aH[3]] + w11[3]*bp_[aH[3]+1];         \
            outp[0] = (t0 + t1) + (t2 + t3);                            \
        }                                                               \
        outp += 49;                                                     \
    } while (0)

    // Waits are exact under in-order vmcnt retirement; see header comment.
#define PIPE(N0, N1, NS, NT) do {                                       \
        STAGE(0, 0); STAGE(1, 1);                                       \
        STAGE(2, 2); VMW(N0); COMP(0);                                  \
        STAGE(3, 0); VMW(N1); COMP(1);                                  \
        int pl = 2, sp = 0;                                             \
        for (int c = 2; c < WCH-2; ++c) {                               \
            sp = (sp == 2) ? 0 : sp + 1;                                \
            STAGE(c+2, sp);                                             \
            VMW(NS); COMP(pl);                                          \
            pl = (pl == 2) ? 0 : pl + 1;                                \
        }                                                               \
        VMW(NT); COMP(pl); pl = (pl == 2) ? 0 : pl + 1;                 \
        VMW(2);  COMP(pl);                                              \
    } while (0)

    if (!LI2) PIPE(2, 3, 4, 3);     // L=1: waits 2L, 2L+1, 2L+2, L+2, 2
    else      PIPE(4, 5, 6, 4);     // L=2

#undef STAGE
#undef COMP
#undef PIPE
}

extern "C" void kernel_launch(void* const* d_in, const int* in_sizes, int n_in,
                              void* d_out, int out_size, void* d_ws, size_t ws_size,
                              hipStream_t stream) {
    const float* feat = (const float*)d_in[0];
    const float* rois = (const float*)d_in[1];
    float*       outp = (float*)d_out;
    const int K = in_sizes[1] / 5;   // 1024
    roialign_kernel<<<K*2, 256, 0, stream>>>(feat, rois, outp);
}

// Round 9
// 131.891 us; speedup vs baseline: 1.0178x; 1.0178x over previous
//
#include <hip/hip_runtime.h>

#define CCH   256
#define FH    96
#define FW    96
#define HW    (FH*FW)
#define SCALE 0.0625f

#define HROWS 21              // max window rows
#define SQMAX 7               // max row stride in quads (runtime sQ in {3,5,7})
#define PLANE (HROWS*SQMAX*4) // 588 floats per plane (fixed alloc, runtime stride)
#define WCH   16              // channels per wave (block = 64ch quarter-roi, 4 waves)

// R9 = R7 (quarter-split, 59.0us best) + FAT ITERATIONS: 2 channels per loop
// iteration with 2 LDS planes/wave (even/odd ping-pong). Evidence: across 9
// rounds, dur tracks wave-iteration count x ~100-140cy and is INSENSITIVE to
// HBM bytes (R5), DS traffic (R6), prefetch depth (R1/R3/R8), imbalance (R7).
// The untouched term is per-iteration serial overhead (~40-60cy: vmcnt wait
// on ds_write, exec toggles, loop/addr chains, lgkm stall). Fat iters halve
// iteration boundaries at IDENTICAL DS/VMEM instruction totals: one vmcnt
// wait per 2 channels, one 16-wide ds_read2 ILP region, one loop boundary.
// Compute reads unpredicated (lanes>=49 broadcast lane-0 addrs = free).
// LDS 2 planes x 4 waves = 18816B -> still 8 blocks/CU.
// SPILL TRIPWIRE: 4 staging float4 under cap-64; if WRITE_SIZE >70MB ->
// spilled (R3 pathology) -> revert to R7.
// Dead ends (do not revisit): reg deep-prefetch (R1/R3), y-fold (R2/R6),
// FETCH reduction (R5), DMA ring (R8), XCD swizzle (R1).
__global__ __launch_bounds__(256, 8)
void roialign_kernel(const float* __restrict__ feat,
                     const float* __restrict__ rois,
                     float* __restrict__ out)
{
    __shared__ __align__(16) float win[4 * 2 * PLANE];   // 18816 B
    __shared__ int   s_lo[2][14];
    __shared__ float s_wl[2][14], s_wh[2][14];

    const int k    = blockIdx.x >> 2;    // identity mapping; 4 quarters per roi
    const int quar = blockIdx.x & 3;
    const int tid  = threadIdx.x;
    const int w    = tid >> 6;
    const int ll   = tid & 63;

    // ---------- Phase A: per-roi sample coords ----------
    const float x1 = rois[k*5+1] * SCALE;
    const float y1 = rois[k*5+2] * SCALE;
    const float x2 = rois[k*5+3] * SCALE;
    const float y2 = rois[k*5+4] * SCALE;
    const int   b  = (int)rois[k*5+0];
    const float binw = fmaxf(x2 - x1, 1.0f) * (1.0f/7.0f);
    const float binh = fmaxf(y2 - y1, 1.0f) * (1.0f/7.0f);

    if (tid < 28) {
        const int   axis  = (tid >= 14) ? 1 : 0;
        const int   g     = axis ? tid - 14 : tid;
        const float start = axis ? x1 : y1;
        const float bsz   = axis ? binw : binh;
        const float offs  = (float)(g >> 1) + 0.25f + 0.5f*(float)(g & 1);
        const float coord = start + bsz * offs;
        const bool  valid = (coord >= -1.0f) && (coord <= 96.0f);
        const float cc    = fminf(fmaxf(coord, 0.0f), 95.0f);
        const float lof   = floorf(cc);
        const float frac  = cc - lof;
        const float v     = valid ? 1.0f : 0.0f;
        s_lo[axis][g] = (int)lof;
        s_wl[axis][g] = (1.0f - frac) * v;
        s_wh[axis][g] = frac * v;
    }
    __syncthreads();   // the ONLY barrier

    // ---------- adaptive window geometry (block-uniform) ----------
    const int row0   = s_lo[0][0];
    const int col0   = s_lo[1][0] & ~3;               // 16B-aligned left edge
    const int colEnd = min(s_lo[1][13] + 1, FW-1);    // rightmost tap column
    const int width  = colEnd - col0 + 1;             // 1..24
    const int cwq    = min((width + 3) >> 2, 6);      // data quads per row, 1..6
    const int sQ     = ((cwq + 1) & ~1) | 1;          // row stride quads: 3,3,5,5,7,7
    const int RS     = sQ * 4;                        // row stride in floats
    int hw_          = min(s_lo[0][13] + 1, FH-1) - row0 + 1;
    const int hwin   = min(hw_, HROWS);               // defensive clamp
    const int nslot  = hwin * cwq;                    // float4 slots, <=126

    float* const wp0 = &win[w * 2 * PLANE];           // even-channel plane
    float* const wp1 = wp0 + PLANE;                   // odd-channel plane

    // Zero both planes once (294 quads). Pad quads (q >= cwq) are never
    // re-written -> stay 0 for weight-0 taps.
    {
        const float4 z = make_float4(0.f, 0.f, 0.f, 0.f);
        #pragma unroll
        for (int jj = 0; jj < 5; ++jj) {
            const int qq = ll + 64*jj;
            if (qq < 2*PLANE/4) *(float4*)&wp0[qq*4] = z;
        }
    }

    // ---------- Phase B: tap addresses & pre-scaled weights (channel-invariant) ----------
    const bool active = ll < 49;
    const int  p  = active ? ll : 0;   // inactive lanes alias p=0 (broadcast reads)
    const int  oy = p / 7;
    const int  ox = p - oy*7;

    int   aL[4], aH[4];
    float w00[4], w01[4], w10[4], w11[4];
    #pragma unroll
    for (int sy = 0; sy < 2; ++sy) {
        const int   gy  = 2*oy + sy;
        const int   rlo = min(s_lo[0][gy] - row0,              HROWS-1);
        const int   rhi = min(min(s_lo[0][gy]+1, FH-1) - row0, HROWS-1);
        const float wyl = s_wl[0][gy], wyh = s_wh[0][gy];
        #pragma unroll
        for (int sx = 0; sx < 2; ++sx) {
            const int   gx  = 2*ox + sx;
            const int   clo = min(s_lo[1][gx] - col0, RS-2);   // <=4*cwq-1 provable
            const float wxl = s_wl[1][gx], wxh = s_wh[1][gx];
            const int   s   = sy*2 + sx;
            aL[s] = rlo*RS + clo;
            aH[s] = rhi*RS + clo;
            w00[s] = wyl*wxl*0.25f;  w01[s] = wyl*wxh*0.25f;   // 0.25 = sample mean
            w10[s] = wyh*wxl*0.25f;  w11[s] = wyh*wxh*0.25f;
        }
    }

    // ---------- load-slot constants: slots ll and ll+64 of nslot ----------
    const int  sl1 = ll + 64;
    const int  r0  = ll  / cwq, q0 = ll  - r0*cwq;   // runtime div, once per lane
    const int  r1  = sl1 / cwq, q1 = sl1 - r1*cwq;
    const bool L0  = ll  < nslot;
    const bool L1  = sl1 < nslot;
    // Clamped: legal addresses even for predicated-off lanes.
    const int  goff0 = min(row0 + r0, FH-1)*FW + col0 + q0*4;  // col0+4*cwq<=96
    const int  goff1 = min(row0 + r1, FH-1)*FW + col0 + q1*4;
    const int  ld0   = min(r0, HROWS-1)*RS + q0*4;
    const int  ld1   = min(r1, HROWS-1)*RS + q1*4;

    const int    cb   = quar*64 + w*WCH;             // 64ch quarter, 16ch/wave
    const float* gch  = feat + (size_t)(b*CCH + cb) * HW;
    float*       outp = out  + ((size_t)k*CCH + cb)*49 + p;

    // ---------- staging prologue: channels 0 (A) and 1 (B) in flight ----------
    float4 sA0, sA1, sB0, sB1;
    if (L0) sA0 = *(const float4*)(gch + goff0);
    if (L1) sA1 = *(const float4*)(gch + goff1);
    {
        const float* gB = gch + HW;
        if (L0) sB0 = *(const float4*)(gB + goff0);
        if (L1) sB1 = *(const float4*)(gB + goff1);
    }

    for (int c = 0; c < WCH; c += 2) {
        // One vmcnt wait covers all 4 writes (both channels' loads drained).
        // Within-wave DS program order: previous iter's reads of wp0/wp1
        // precede these writes; this iter's reads follow them.
        if (L0) *(float4*)&wp0[ld0] = sA0;
        if (L1) *(float4*)&wp0[ld1] = sA1;
        if (L0) *(float4*)&wp1[ld0] = sB0;
        if (L1) *(float4*)&wp1[ld1] = sB1;

        if (c + 2 < WCH) {                 // channels c+2/c+3 in flight during compute
            const float* gA = gch + (size_t)(c+2) * HW;
            const float* gB = gA + HW;
            if (L0) sA0 = *(const float4*)(gA + goff0);
            if (L1) sA1 = *(const float4*)(gA + goff1);
            if (L0) sB0 = *(const float4*)(gB + goff0);
            if (L1) sB1 = *(const float4*)(gB + goff1);
        }

        // Compute both channels: 16 independent ds_read2 in one ILP region.
        // Reads unpredicated (lanes>=49 broadcast p=0 addrs, free); stores
        // keep the 49-lane predicate.
        float a0 = w00[0]*wp0[aL[0]] + w01[0]*wp0[aL[0]+1]
                 + w10[0]*wp0[aH[0]] + w11[0]*wp0[aH[0]+1];
        float a1 = w00[1]*wp0[aL[1]] + w01[1]*wp0[aL[1]+1]
                 + w10[1]*wp0[aH[1]] + w11[1]*wp0[aH[1]+1];
        float a2 = w00[2]*wp0[aL[2]] + w01[2]*wp0[aL[2]+1]
                 + w10[2]*wp0[aH[2]] + w11[2]*wp0[aH[2]+1];
        float a3 = w00[3]*wp0[aL[3]] + w01[3]*wp0[aL[3]+1]
                 + w10[3]*wp0[aH[3]] + w11[3]*wp0[aH[3]+1];
        float b0 = w00[0]*wp1[aL[0]] + w01[0]*wp1[aL[0]+1]
                 + w10[0]*wp1[aH[0]] + w11[0]*wp1[aH[0]+1];
        float b1 = w00[1]*wp1[aL[1]] + w01[1]*wp1[aL[1]+1]
                 + w10[1]*wp1[aH[1]] + w11[1]*wp1[aH[1]+1];
        float b2 = w00[2]*wp1[aL[2]] + w01[2]*wp1[aL[2]+1]
                 + w10[2]*wp1[aH[2]] + w11[2]*wp1[aH[2]+1];
        float b3 = w00[3]*wp1[aL[3]] + w01[3]*wp1[aL[3]+1]
                 + w10[3]*wp1[aH[3]] + w11[3]*wp1[aH[3]+1];
        if (active) {
            outp[0]  = (a0 + a1) + (a2 + a3);
            outp[49] = (b0 + b1) + (b2 + b3);
        }
        outp += 98;
    }
}

extern "C" void kernel_launch(void* const* d_in, const int* in_sizes, int n_in,
                              void* d_out, int out_size, void* d_ws, size_t ws_size,
                              hipStream_t stream) {
    const float* feat = (const float*)d_in[0];
    const float* rois = (const float*)d_in[1];
    float*       outp = (float*)d_out;
    const int K = in_sizes[1] / 5;   // 1024
    roialign_kernel<<<K*4, 256, 0, stream>>>(feat, rois, outp);
}